// Round 9
// baseline (279.816 us; speedup 1.0000x reference)
//
#include <hip/hip_runtime.h>
#include <stdint.h>

#define N_TOKENS 8192
#define IN_DIM   1024
#define OUT_DIM  1024
#define NE       8
#define HID      64

typedef __attribute__((ext_vector_type(8))) short bf16x8;   // 8 bf16 = 4 VGPR
typedef __attribute__((ext_vector_type(4))) float f32x4;

// ---------------- helpers ----------------
__device__ __forceinline__ unsigned short f2bf(float f) {   // RN-even fp32->bf16
    unsigned int b = __float_as_uint(f);
    b += 0x7fffu + ((b >> 16) & 1u);
    return (unsigned short)(b >> 16);
}
__device__ __forceinline__ float bf2f(unsigned short u) {
    return __uint_as_float(((unsigned int)u) << 16);
}

__device__ __forceinline__ void gl16(const unsigned short* g, unsigned short* l) {
    __builtin_amdgcn_global_load_lds(
        (const __attribute__((address_space(1))) unsigned int*)g,
        (__attribute__((address_space(3))) unsigned int*)l,
        16, 0, 0);
}

// =================== fp32 -> bf16 (We) ===================
__global__ __launch_bounds__(256) void conv_bf16(
    const float* __restrict__ src, unsigned short* __restrict__ dst, int n4)
{
    int i = blockIdx.x * 256 + threadIdx.x;
    const int stride = gridDim.x * 256;
    for (; i < n4; i += stride) {
        float4 v = ((const float4*)src)[i];
        ushort4 h;
        h.x = f2bf(v.x); h.y = f2bf(v.y); h.z = f2bf(v.z); h.w = f2bf(v.w);
        ((ushort4*)dst)[i] = h;
    }
}

// =================== fp32 -> bf16 hi/lo split (Wg1) ===================
__global__ __launch_bounds__(256) void split_wg1(
    const float* __restrict__ src, unsigned short* __restrict__ hi,
    unsigned short* __restrict__ lo, int n4)
{
    int i = blockIdx.x * 256 + threadIdx.x;
    if (i >= n4) return;
    float4 v = ((const float4*)src)[i];
    ushort4 h, l;
    h.x = f2bf(v.x); l.x = f2bf(v.x - bf2f(h.x));
    h.y = f2bf(v.y); l.y = f2bf(v.y - bf2f(h.y));
    h.z = f2bf(v.z); l.z = f2bf(v.z - bf2f(h.z));
    h.w = f2bf(v.w); l.w = f2bf(v.w - bf2f(h.w));
    ((ushort4*)hi)[i] = h;
    ((ushort4*)lo)[i] = l;
}

// =================== gating (split-2 bf16 MFMA, x prefetch) ===================
__global__ __launch_bounds__(256) void gating_kernel(
    const float* __restrict__ x, unsigned short* __restrict__ xh_out,
    const unsigned short* __restrict__ wg1h, const unsigned short* __restrict__ wg1l,
    const float* __restrict__ bg1,
    const float* __restrict__ Wg2, const float* __restrict__ bg2,
    float* __restrict__ out_gw, float* __restrict__ out_idx,
    int* __restrict__ counts, int* __restrict__ bucket_tok, float* __restrict__ bucket_w)
{
    __shared__ unsigned short Xh_s[64 * 32], Xl_s[64 * 32];   // [tok][k]
    __shared__ unsigned short Gh_s[64 * 32], Gl_s[64 * 32];   // [hid][k]
    __shared__ float Hs[64][68];
    __shared__ float W2s[NE][HID];
    __shared__ float b2s[NE];

    const int tid  = threadIdx.x;
    const int wv   = tid >> 6;
    const int lane = tid & 63;
    const int t0   = blockIdx.x * 64;

    for (int i = tid; i < NE * HID; i += 256) W2s[i >> 6][i & 63] = Wg2[i];
    if (tid < NE) b2s[tid] = bg2[tid];

    const int r = tid >> 2;            // 0..63 token row
    const int c = tid & 3;             // k-chunk (8 floats)
    const float* xsrc = x + (size_t)(t0 + r) * IN_DIM + c * 8;
    unsigned short* xdst = xh_out + (size_t)(t0 + r) * IN_DIM + c * 8;

    const unsigned short* gh_src = wg1h + (size_t)(wv * 16 + (lane >> 2)) * IN_DIM + (lane & 3) * 8;
    const unsigned short* gl_src = wg1l + (size_t)(wv * 16 + (lane >> 2)) * IN_DIM + (lane & 3) * 8;
    unsigned short* gh_dst = &Gh_s[wv * 512];
    unsigned short* gl_dst = &Gl_s[wv * 512];

    const int fr = lane & 15;
    const int kb = (lane >> 4) * 8;

    f32x4 acc[4];
#pragma unroll
    for (int mi = 0; mi < 4; ++mi) acc[mi] = (f32x4)0.0f;

    float4 v0 = *(const float4*)(xsrc);
    float4 v1 = *(const float4*)(xsrc + 4);

    for (int k0 = 0; k0 < IN_DIM; k0 += 32) {
        bf16x8 xh8, xl8;
        {
            float vv[8] = {v0.x, v0.y, v0.z, v0.w, v1.x, v1.y, v1.z, v1.w};
#pragma unroll
            for (int j = 0; j < 8; ++j) {
                unsigned short h = f2bf(vv[j]);
                xh8[j] = (short)h;
                xl8[j] = (short)f2bf(vv[j] - bf2f(h));
            }
        }
        *(bf16x8*)(xdst + k0) = xh8;

        __syncthreads();                                 // prev tile reads done
        *(bf16x8*)&Xh_s[r * 32 + c * 8] = xh8;
        *(bf16x8*)&Xl_s[r * 32 + c * 8] = xl8;
        gl16(gh_src + k0, gh_dst);
        gl16(gl_src + k0, gl_dst);
        {   // prefetch next x tile (wrapped; harmless extra on last iter)
            const int k1 = (k0 + 32) & (IN_DIM - 1);
            v0 = *(const float4*)(xsrc + k1);
            v1 = *(const float4*)(xsrc + k1 + 4);
        }
        __syncthreads();                                 // lds + vmcnt drained

        bf16x8 bh = *(const bf16x8*)&Gh_s[(wv * 16 + fr) * 32 + kb];
        bf16x8 bl = *(const bf16x8*)&Gl_s[(wv * 16 + fr) * 32 + kb];
#pragma unroll
        for (int mi = 0; mi < 4; ++mi) {
            bf16x8 ah = *(const bf16x8*)&Xh_s[(mi * 16 + fr) * 32 + kb];
            bf16x8 al = *(const bf16x8*)&Xl_s[(mi * 16 + fr) * 32 + kb];
            acc[mi] = __builtin_amdgcn_mfma_f32_16x16x32_bf16(ah, bh, acc[mi], 0, 0, 0);
            acc[mi] = __builtin_amdgcn_mfma_f32_16x16x32_bf16(ah, bl, acc[mi], 0, 0, 0);
            acc[mi] = __builtin_amdgcn_mfma_f32_16x16x32_bf16(al, bh, acc[mi], 0, 0, 0);
        }
    }

    const float bgv = bg1[wv * 16 + fr];
#pragma unroll
    for (int mi = 0; mi < 4; ++mi)
#pragma unroll
        for (int rg = 0; rg < 4; ++rg)
            Hs[mi * 16 + (lane >> 4) * 4 + rg][wv * 16 + fr] = fmaxf(acc[mi][rg] + bgv, 0.0f);
    __syncthreads();

    if (tid < 64) {
        const int token = t0 + tid;
        float sc[NE];
#pragma unroll
        for (int e2 = 0; e2 < NE; ++e2) {
            float s = b2s[e2];
#pragma unroll
            for (int j = 0; j < HID; ++j) s += Hs[tid][j] * W2s[e2][j];
            sc[e2] = s;
        }
        float m = sc[0];
#pragma unroll
        for (int e2 = 1; e2 < NE; ++e2) m = fmaxf(m, sc[e2]);
        float sum = 0.0f;
#pragma unroll
        for (int e2 = 0; e2 < NE; ++e2) { sc[e2] = expf(sc[e2] - m); sum += sc[e2]; }
        const float inv = 1.0f / sum;
#pragma unroll
        for (int e2 = 0; e2 < NE; ++e2) { sc[e2] *= inv; out_gw[(size_t)token * NE + e2] = sc[e2]; }

        int i1 = 0; float v1s = sc[0];
#pragma unroll
        for (int e2 = 1; e2 < NE; ++e2) if (sc[e2] > v1s) { v1s = sc[e2]; i1 = e2; }
        int i2 = -1; float v2s = -1e30f;
#pragma unroll
        for (int e2 = 0; e2 < NE; ++e2) {
            if (e2 == i1) continue;
            if (i2 < 0 || sc[e2] > v2s) { v2s = sc[e2]; i2 = e2; }
        }
        out_idx[(size_t)token * 2 + 0] = (float)i1;
        out_idx[(size_t)token * 2 + 1] = (float)i2;

        const unsigned long long lmask = (1ull << tid) - 1ull;
#pragma unroll
        for (int e2 = 0; e2 < NE; ++e2) {
            unsigned long long m1 = __ballot(i1 == e2);
            unsigned long long m2 = __ballot(i2 == e2);
            int c1 = __popcll(m1), c2 = __popcll(m2);
            int base = 0;
            if (tid == 0 && (c1 + c2) > 0) base = atomicAdd(&counts[e2 * 16], c1 + c2);
            base = __shfl(base, 0);
            if (i1 == e2) {
                int pos = base + __popcll(m1 & lmask);
                bucket_tok[e2 * N_TOKENS + pos] = token * 2 + 0;
                bucket_w  [e2 * N_TOKENS + pos] = v1s;
            }
            if (i2 == e2) {
                int pos = base + c1 + __popcll(m2 & lmask);
                bucket_tok[e2 * N_TOKENS + pos] = token * 2 + 1;
                bucket_w  [e2 * N_TOKENS + pos] = v2s;
            }
        }
    }
}

// =================== grouped expert GEMM v2 ===================
// 128x128 tile, KS=64, reg-staged (issue-early/write-late), XOR-swizzled LDS,
// bf16 tmp output. grid(tt=64, ot=8, e=8) so the 8 ot-blocks of a family
// share an XCD (ids differ by 64 == 0 mod 8) -> X-panel L2 reuse.
#define BM 128
#define KS 64

__global__ __launch_bounds__(256) void expert_gemm(
    const unsigned short* __restrict__ xh, const unsigned short* __restrict__ wh,
    const float* __restrict__ be, const int* __restrict__ counts,
    const int* __restrict__ bucket_tok, const float* __restrict__ bucket_w,
    unsigned short* __restrict__ tmp)
{
    const int tt = blockIdx.x;
    const int ot = blockIdx.y;
    const int e  = blockIdx.z;
    const int cnt = counts[e * 16];
    if (tt * BM >= cnt) return;

    __shared__ unsigned short Xs[BM * KS];   // 16KB, swizzled [row][k]
    __shared__ unsigned short Ws[BM * KS];   // 16KB
    __shared__ int   slt[BM];
    __shared__ float wts[BM];

    const int tid  = threadIdx.x;
    const int wv   = tid >> 6;
    const int lane = tid & 63;

    if (tid < BM) {
        int idx = tt * BM + tid;
        slt[tid] = (idx < cnt) ? bucket_tok[e * N_TOKENS + idx] : -1;
        wts[tid] = (idx < cnt) ? bucket_w [e * N_TOKENS + idx] : 0.0f;
    }
    __syncthreads();

    // staging: lane -> row wv*32 + (lane>>1), k-half lane&1 (64B of 128B row)
    const int srow  = wv * 32 + (lane >> 1);
    const int khalf = lane & 1;
    const int sx    = slt[srow];
    const int stok  = (sx < 0) ? 0 : (sx >> 1);
    const unsigned short* gX = xh + (size_t)stok * IN_DIM + khalf * 32;
    const unsigned short* gW = wh + ((size_t)e * OUT_DIM + ot * BM + srow) * IN_DIM + khalf * 32;

    // swizzled write offsets (elems): row*64 + ((khalf*32 + c*8) ^ ((row&7)<<3))
    int wofs[4];
#pragma unroll
    for (int cc = 0; cc < 4; ++cc)
        wofs[cc] = srow * KS + (((khalf * 32 + cc * 8) ^ ((srow & 7) << 3)));

    const int wm = wv >> 1, wn = wv & 1;
    const int fr  = lane & 15;
    const int kbq = (lane >> 4);            // 0..3

    f32x4 acc[4][4];
#pragma unroll
    for (int mi = 0; mi < 4; ++mi)
#pragma unroll
        for (int ni = 0; ni < 4; ++ni) acc[mi][ni] = (f32x4)0.0f;

    // prefetch k0 = 0
    bf16x8 rX[4], rW[4];
#pragma unroll
    for (int cc = 0; cc < 4; ++cc) {
        rX[cc] = *(const bf16x8*)(gX + cc * 8);
        rW[cc] = *(const bf16x8*)(gW + cc * 8);
    }

    for (int k0 = 0; k0 < IN_DIM; k0 += KS) {
        // write current tile to swizzled LDS
#pragma unroll
        for (int cc = 0; cc < 4; ++cc) {
            *(bf16x8*)&Xs[wofs[cc]] = rX[cc];
            *(bf16x8*)&Ws[wofs[cc]] = rW[cc];
        }
        // issue next tile loads (wrapped on last iter; harmless)
        {
            const int k1 = (k0 + KS) & (IN_DIM - 1);
#pragma unroll
            for (int cc = 0; cc < 4; ++cc) {
                rX[cc] = *(const bf16x8*)(gX + k1 + cc * 8);
                rW[cc] = *(const bf16x8*)(gW + k1 + cc * 8);
            }
        }
        __syncthreads();   // tile visible

#pragma unroll
        for (int ks = 0; ks < 2; ++ks) {
            bf16x8 ah[4], bh[4];
#pragma unroll
            for (int mi = 0; mi < 4; ++mi) {
                const int row = wm * 64 + mi * 16 + fr;
                ah[mi] = *(const bf16x8*)&Xs[row * KS + ((ks * 32 + kbq * 8) ^ ((row & 7) << 3))];
            }
#pragma unroll
            for (int ni = 0; ni < 4; ++ni) {
                const int row = wn * 64 + ni * 16 + fr;
                bh[ni] = *(const bf16x8*)&Ws[row * KS + ((ks * 32 + kbq * 8) ^ ((row & 7) << 3))];
            }
#pragma unroll
            for (int mi = 0; mi < 4; ++mi)
#pragma unroll
                for (int ni = 0; ni < 4; ++ni)
                    acc[mi][ni] = __builtin_amdgcn_mfma_f32_16x16x32_bf16(ah[mi], bh[ni], acc[mi][ni], 0, 0, 0);
        }
        __syncthreads();   // reads done before next writes
    }

    // epilogue: tmp[slot] = bf16(w * (acc + bias)); C/D col=lane&15, row=(lane>>4)*4+r
    const int colbase = ot * BM + wn * 64;
    float bias[4];
#pragma unroll
    for (int ni = 0; ni < 4; ++ni) bias[ni] = be[(size_t)e * OUT_DIM + colbase + ni * 16 + fr];

#pragma unroll
    for (int mi = 0; mi < 4; ++mi) {
#pragma unroll
        for (int r2 = 0; r2 < 4; ++r2) {
            const int ri = wm * 64 + mi * 16 + (lane >> 4) * 4 + r2;
            const int s  = slt[ri];
            if (s < 0) continue;
            const float w = wts[ri];
            unsigned short* orow = tmp + (size_t)s * OUT_DIM + colbase;
#pragma unroll
            for (int ni = 0; ni < 4; ++ni)
                orow[ni * 16 + fr] = f2bf(w * (acc[mi][ni][r2] + bias[ni]));
        }
    }
}

// =================== combine: out[t] = tmp[2t] + tmp[2t+1] (bf16 in) ===================
__global__ __launch_bounds__(256) void combine_kernel(
    const unsigned short* __restrict__ tmp, float* __restrict__ out, int n8)
{
    int i = blockIdx.x * 256 + threadIdx.x;
    if (i >= n8) return;
    const int t  = i >> 7;              // OUT_DIM/8 = 128 chunks per row
    const int d8 = (i & 127) * 8;
    const unsigned short* a = tmp + (size_t)(2 * t) * OUT_DIM + d8;
    const unsigned short* b = tmp + (size_t)(2 * t + 1) * OUT_DIM + d8;
    bf16x8 av = *(const bf16x8*)a;
    bf16x8 bv = *(const bf16x8*)b;
    float o[8];
#pragma unroll
    for (int j = 0; j < 8; ++j)
        o[j] = bf2f((unsigned short)av[j]) + bf2f((unsigned short)bv[j]);
    float* orow = out + (size_t)t * OUT_DIM + d8;
    *(float4*)(orow)     = make_float4(o[0], o[1], o[2], o[3]);
    *(float4*)(orow + 4) = make_float4(o[4], o[5], o[6], o[7]);
}

// =================== launch ===================
extern "C" void kernel_launch(void* const* d_in, const int* in_sizes, int n_in,
                              void* d_out, int out_size, void* d_ws, size_t ws_size,
                              hipStream_t stream) {
    const float* x   = (const float*)d_in[0];
    const float* We  = (const float*)d_in[1];
    const float* be  = (const float*)d_in[2];
    const float* Wg1 = (const float*)d_in[3];
    const float* bg1 = (const float*)d_in[4];
    const float* Wg2 = (const float*)d_in[5];
    const float* bg2 = (const float*)d_in[6];

    float* out     = (float*)d_out;
    float* out_gw  = out + (size_t)N_TOKENS * OUT_DIM;     // [N, 8]
    float* out_idx = out_gw + (size_t)N_TOKENS * NE;       // [N, 2] as float

    char* ws = (char*)d_ws;
    int*   counts = (int*)ws;                               // stride-16 counters
    int*   btok   = (int*)(ws + 1024);
    float* bw     = (float*)(ws + 1024 + 262144);
    unsigned short* xh   = (unsigned short*)(ws + 525312);           // 16 MB
    unsigned short* wh   = xh + (size_t)N_TOKENS * IN_DIM;           // 16 MB
    unsigned short* wg1h = wh + (size_t)NE * OUT_DIM * IN_DIM;       // 128 KB
    unsigned short* wg1l = wg1h + (size_t)HID * IN_DIM;              // 128 KB
    unsigned short* tmp  = wg1l + (size_t)HID * IN_DIM;              // 32 MB bf16

    hipMemsetAsync(counts, 0, 1024, stream);

    split_wg1<<<64, 256, 0, stream>>>(Wg1, wg1h, wg1l, (HID * IN_DIM) / 4);
    conv_bf16<<<1024, 256, 0, stream>>>(We, wh, (NE * OUT_DIM * IN_DIM) / 4);

    gating_kernel<<<N_TOKENS / 64, 256, 0, stream>>>(
        x, xh, wg1h, wg1l, bg1, Wg2, bg2, out_gw, out_idx, counts, btok, bw);

    dim3 grid(N_TOKENS / BM, OUT_DIM / BM, NE);   // (tt, ot, e) family-clustered
    expert_gemm<<<grid, 256, 0, stream>>>(xh, wh, be, counts, btok, bw, tmp);

    combine_kernel<<<(N_TOKENS * OUT_DIM / 8 + 255) / 256, 256, 0, stream>>>(
        tmp, out, N_TOKENS * OUT_DIM / 8);
}